// Round 7
// baseline (255.177 us; speedup 1.0000x reference)
//
#include <hip/hip_runtime.h>
#include <hip/hip_bf16.h>
#include <math.h>

// Pipeline: x[16,256,256,256] --8x8 avgpool--> [16,256,32,32] --dw3x3-->
// GN(8)+SiLU --pw 256->16--> GN(4)+SiLU --pw 16->8 +bias--> softmax(E) -->
// spatial mean --> top-2 + renorm. Memory-bound on the 1.07 GB input read.
//
// K1: fused pool + dw3x3 + GN1 partials. Block sweeps its 256KB plane
//     LINEARLY (one contiguous 8KB front across the 4 waves). This round:
//     PLAIN (cached) loads instead of NT — A/B on the nt flag only.
// K2: GN1 finalize + SiLU + pw C->R + GN2 partials
// K3: GN2 finalize + SiLU + pw R->E + softmax + mean + top2

#define C_    256
#define HWIN  256
#define OHW   32
#define NPIX  1024   // 32*32
#define R_    16
#define E_    8

using f4 = __attribute__((ext_vector_type(4))) float;

// ---------------- K1: linear-sweep pool + depthwise 3x3 + GN1 partials ------
__global__ __launch_bounds__(256) void k1_pool_dw(
    const float* __restrict__ x, const float* __restrict__ wdw,
    float* __restrict__ h1, float* __restrict__ ch_sum,
    float* __restrict__ ch_sumsq) {
  const int bc   = blockIdx.x;          // b*256 + c
  const int c    = bc & (C_ - 1);
  const int tid  = threadIdx.x;
  const int wv   = tid >> 6, lane = tid & 63;
  const float* plane = x + (size_t)bc * (HWIN * HWIN);

  // part[pr][w][col]: per-wave 2-row partial sums; pooled combined in place
  __shared__ float part[OHW][4][32];

  // Linear plane sweep: at step pr the block's 4 waves read input rows
  // {8pr+0..3} and {8pr+4..7} -> one contiguous 8KB front.
#pragma unroll 4
  for (int pr = 0; pr < OHW; ++pr) {
    const float* r0 = plane + ((size_t)(8 * pr + wv)) * HWIN + lane * 4;
    const f4 a = *reinterpret_cast<const f4*>(r0);                 // plain load
    const f4 b = *reinterpret_cast<const f4*>(r0 + 4 * HWIN);      // plain load
    const f4 v = a + b;
    float s = (v.x + v.y) + (v.z + v.w);
    s += __shfl_xor(s, 1);                     // 8-col sum for col lane>>1
    if (!(lane & 1)) part[pr][wv][lane >> 1] = s;
  }
  float w[9];
#pragma unroll
  for (int i = 0; i < 9; ++i) w[i] = wdw[c * 9 + i];
  __syncthreads();

  // combine 4 wave-partials -> pooled value, in place over part[pr][0][col]
  for (int p = tid; p < NPIX; p += 256) {
    const int oh = p >> 5, ow = p & 31;
    const float v = ((part[oh][0][ow] + part[oh][1][ow]) +
                     (part[oh][2][ow] + part[oh][3][ow])) * (1.f / 64.f);
    part[oh][0][ow] = v;                       // each (oh,ow) owned by 1 thread
  }
  __syncthreads();

#define SM(y, xx) part[y][0][xx]
  // depthwise 3x3 SAME (zero pad) + local stats
  float ls = 0.f, lss = 0.f;
  for (int p = tid; p < NPIX; p += 256) {
    const int oh = p >> 5, ow = p & 31;
    float acc = 0.f;
#pragma unroll
    for (int ky = 0; ky < 3; ++ky) {
      const int y = oh + ky - 1;
      if ((unsigned)y >= OHW) continue;
#pragma unroll
      for (int kx = 0; kx < 3; ++kx) {
        const int xx = ow + kx - 1;
        if ((unsigned)xx >= OHW) continue;
        acc += w[ky * 3 + kx] * SM(y, xx);
      }
    }
    h1[(size_t)bc * NPIX + p] = acc;
    ls += acc; lss += acc * acc;
  }
#undef SM

  // deterministic block reduce -> per-channel sums
#pragma unroll
  for (int m = 32; m >= 1; m >>= 1) {
    ls  += __shfl_xor(ls, m);
    lss += __shfl_xor(lss, m);
  }
  __shared__ float r2[4][2];
  if (lane == 0) { r2[wv][0] = ls; r2[wv][1] = lss; }
  __syncthreads();
  if (tid == 0) {
    ch_sum[bc]   = (r2[0][0] + r2[1][0]) + (r2[2][0] + r2[3][0]);
    ch_sumsq[bc] = (r2[0][1] + r2[1][1]) + (r2[2][1] + r2[3][1]);
  }
}

// -------- K2: GN1 finalize + SiLU + pointwise C->R + GN2 partial stats ------
__global__ __launch_bounds__(256) void k2_pw1(
    const float* __restrict__ h1, const float* __restrict__ ch_sum,
    const float* __restrict__ ch_sumsq, const float* __restrict__ g1,
    const float* __restrict__ b1, const float* __restrict__ w1,
    float* __restrict__ h2, float* __restrict__ st2) {
  const int blk = blockIdx.x;          // b*16 + q
  const int b   = blk >> 4, q = blk & 15;
  const int tid = threadIdx.x;
  const int wv  = tid >> 6, lane = tid & 63;

  __shared__ float musr[8][2];
  __shared__ float sc[C_], sh[C_];
  __shared__ float w1s[R_ * C_];          // 16 KB
  __shared__ float red[4][64][R_ + 1];    // padded: kills bank conflicts

  {
    float cs  = ch_sum[b * C_ + tid];
    float css = ch_sumsq[b * C_ + tid];
#pragma unroll
    for (int m = 16; m >= 1; m >>= 1) {
      cs  += __shfl_xor(cs, m);
      css += __shfl_xor(css, m);
    }
    if ((tid & 31) == 0) {
      const int g = tid >> 5;
      const float mu  = cs * (1.f / 32768.f);
      const float var = css * (1.f / 32768.f) - mu * mu;
      musr[g][0] = mu;
      musr[g][1] = rsqrtf(var + 1e-5f);
    }
  }
  for (int i = tid; i < R_ * C_; i += 256) w1s[i] = w1[i];
  __syncthreads();

  {
    const int g = tid >> 5;
    const float mu = musr[g][0], rs = musr[g][1];
    const float ga = g1[tid];
    sc[tid] = rs * ga;
    sh[tid] = b1[tid] - mu * rs * ga;
  }
  __syncthreads();

  const int hw = q * 64 + lane;
  const float* hp = h1 + (size_t)b * C_ * NPIX + hw;
  const int c0 = wv * 64;
  float acc[R_];
#pragma unroll
  for (int r = 0; r < R_; ++r) acc[r] = 0.f;

#pragma unroll 8
  for (int j = 0; j < 64; ++j) {
    const int cc = c0 + j;
    const float v = hp[(size_t)cc * NPIX];          // coalesced across lanes
    const float u = v * sc[cc] + sh[cc];
    const float t = u / (1.f + __expf(-u));         // SiLU
#pragma unroll
    for (int r = 0; r < R_; ++r) acc[r] += t * w1s[r * C_ + cc];
  }

#pragma unroll
  for (int r = 0; r < R_; ++r) red[wv][lane][r] = acc[r];
  __syncthreads();

  // thread t: pixel p = t>>2, r-group g = t&3 (r = 4g..4g+3)
  const int p = tid >> 2, g = tid & 3;
  float gs = 0.f, gss = 0.f;
  float* h2p = h2 + (size_t)b * R_ * NPIX + q * 64 + p;
#pragma unroll
  for (int j = 0; j < 4; ++j) {
    const int r = g * 4 + j;
    const float v = (red[0][p][r] + red[1][p][r]) + (red[2][p][r] + red[3][p][r]);
    h2p[r * NPIX] = v;
    gs += v; gss += v * v;
  }
#pragma unroll
  for (int m = 4; m <= 32; m <<= 1) {
    gs  += __shfl_xor(gs, m);
    gss += __shfl_xor(gss, m);
  }
  __shared__ float red2[4][4][2];
  if (lane < 4) { red2[wv][lane][0] = gs; red2[wv][lane][1] = gss; }
  __syncthreads();
  if (tid < 8) {
    const int gg = tid >> 1, which = tid & 1;
    st2[blk * 8 + tid] = (red2[0][gg][which] + red2[1][gg][which]) +
                         (red2[2][gg][which] + red2[3][gg][which]);
  }
}

// ---- K3: GN2 finalize + SiLU + pw R->E + softmax + mean + top-2 + renorm ---
__global__ __launch_bounds__(256) void k3_route(
    const float* __restrict__ h2, const float* __restrict__ st2,
    const float* __restrict__ g2, const float* __restrict__ b2,
    const float* __restrict__ w2, const float* __restrict__ bias2,
    float* __restrict__ out) {
  const int b   = blockIdx.x;
  const int tid = threadIdx.x;

  __shared__ float musr[4][2];
  __shared__ float sc2[R_], sh2[R_];
  __shared__ float w2s[E_ * R_ + E_];

  if (tid < 4) {
    float s = 0.f, ss = 0.f;
    for (int qq = 0; qq < 16; ++qq) {
      s  += st2[(b * 16 + qq) * 8 + tid * 2];
      ss += st2[(b * 16 + qq) * 8 + tid * 2 + 1];
    }
    const float mu  = s * (1.f / 4096.f);
    const float var = ss * (1.f / 4096.f) - mu * mu;
    musr[tid][0] = mu;
    musr[tid][1] = rsqrtf(var + 1e-5f);
  }
  if (tid < E_ * R_) w2s[tid] = w2[tid];
  else if (tid < E_ * R_ + E_) w2s[tid] = bias2[tid - E_ * R_];
  __syncthreads();
  if (tid < R_) {
    const int g = tid >> 2;
    const float ga = g2[tid];
    sc2[tid] = musr[g][1] * ga;
    sh2[tid] = b2[tid] - musr[g][0] * musr[g][1] * ga;
  }
  __syncthreads();

  float wa[E_];
#pragma unroll
  for (int e = 0; e < E_; ++e) wa[e] = 0.f;
  const float* hp = h2 + (size_t)b * R_ * NPIX;

  for (int pp = 0; pp < 4; ++pp) {
    const int hw = pp * 256 + tid;
    float t[R_];
#pragma unroll
    for (int r = 0; r < R_; ++r) {
      const float u = hp[r * NPIX + hw] * sc2[r] + sh2[r];
      t[r] = u / (1.f + __expf(-u));
    }
    float lg[E_];
    float mx = -1e30f;
#pragma unroll
    for (int e = 0; e < E_; ++e) {
      float s = w2s[E_ * R_ + e];
#pragma unroll
      for (int r = 0; r < R_; ++r) s += w2s[e * R_ + r] * t[r];
      lg[e] = s;
      mx = fmaxf(mx, s);
    }
    float den = 0.f;
#pragma unroll
    for (int e = 0; e < E_; ++e) { lg[e] = __expf(lg[e] - mx); den += lg[e]; }
    const float inv = 1.f / den;
#pragma unroll
    for (int e = 0; e < E_; ++e) wa[e] += lg[e] * inv;
  }

#pragma unroll
  for (int m = 32; m >= 1; m >>= 1) {
#pragma unroll
    for (int e = 0; e < E_; ++e) wa[e] += __shfl_xor(wa[e], m);
  }
  __shared__ float red[4][E_];
  const int wv = tid >> 6;
  if ((tid & 63) == 0) {
#pragma unroll
    for (int e = 0; e < E_; ++e) red[wv][e] = wa[e];
  }
  __syncthreads();
  __shared__ float pooled[E_];
  if (tid < E_)
    pooled[tid] = ((red[0][tid] + red[1][tid]) + (red[2][tid] + red[3][tid])) * (1.f / 1024.f);
  __syncthreads();

  if (tid == 0) {
    float pv[E_];
#pragma unroll
    for (int e = 0; e < E_; ++e) pv[e] = pooled[e];
    // top-2, strict > keeps lowest index on ties (lax.top_k semantics)
    int i1 = 0; float v1 = pv[0];
    for (int e = 1; e < E_; ++e) if (pv[e] > v1) { v1 = pv[e]; i1 = e; }
    pv[i1] = -1e30f;
    int i2 = 0; float v2 = pv[0];
    for (int e = 1; e < E_; ++e) if (pv[e] > v2) { v2 = pv[e]; i2 = e; }
    const float inv = 1.f / (v1 + v2 + 1e-9f);
    out[b * 2 + 0] = v1 * inv;
    out[b * 2 + 1] = v2 * inv;
    out[32 + b * 2 + 0] = (float)i1;   // indices as fp32 (whole d_out read as f32)
    out[32 + b * 2 + 1] = (float)i2;
  }
}

extern "C" void kernel_launch(void* const* d_in, const int* in_sizes, int n_in,
                              void* d_out, int out_size, void* d_ws, size_t ws_size,
                              hipStream_t stream) {
  const float* x     = (const float*)d_in[0];
  const float* wdw   = (const float*)d_in[1];
  const float* g1    = (const float*)d_in[2];
  const float* b1    = (const float*)d_in[3];
  const float* w1    = (const float*)d_in[4];
  const float* g2    = (const float*)d_in[5];
  const float* b2    = (const float*)d_in[6];
  const float* w2    = (const float*)d_in[7];
  const float* bias2 = (const float*)d_in[8];
  float* out = (float*)d_out;

  char* ws = (char*)d_ws;
  float* h1       = (float*)ws;                              // 16 MiB
  float* h2       = (float*)(ws + (size_t)16 * 1024 * 1024); // 1 MiB
  float* ch_sum   = (float*)(ws + (size_t)17 * 1024 * 1024); // 16 KiB
  float* ch_sumsq = ch_sum + 4096;                           // 16 KiB
  float* st2      = ch_sumsq + 4096;                         // 8 KiB

  hipLaunchKernelGGL(k1_pool_dw, dim3(16 * C_), dim3(256), 0, stream,
                     x, wdw, h1, ch_sum, ch_sumsq);
  hipLaunchKernelGGL(k2_pw1, dim3(256), dim3(256), 0, stream,
                     h1, ch_sum, ch_sumsq, g1, b1, w1, h2, st2);
  hipLaunchKernelGGL(k3_route, dim3(16), dim3(256), 0, stream,
                     h2, st2, g2, b2, w2, bias2, out);
}

// Round 8
// 234.740 us; speedup vs baseline: 1.0871x; 1.0871x over previous
//
#include <hip/hip_runtime.h>
#include <hip/hip_bf16.h>
#include <math.h>

// Pipeline: x[16,256,256,256] --8x8 avgpool--> [16,256,32,32] --dw3x3-->
// GN(8)+SiLU --pw 256->16--> GN(4)+SiLU --pw 16->8 +bias--> softmax(E) -->
// spatial mean --> top-2 + renorm. Memory-bound on the 1.07 GB input read.
//
// K1: pool via global_load_lds 3-deep ring + counted vmcnt (never 0 in loop):
//     raises in-flight read bytes ~20x over register landing (Little's law).
//     Then dw3x3 + GN1 partials from LDS. NT cache policy (aux=2).
// K2: GN1 finalize + SiLU + pw C->R + GN2 partials
// K3: GN2 finalize + SiLU + pw R->E + softmax + mean + top2

#define C_    256
#define HWIN  256
#define OHW   32
#define NPIX  1024   // 32*32
#define R_    16
#define E_    8

#define CHUNK_F 2048   // 8 rows * 256 cols: one pooled row per chunk
#define NCHUNK  32
#define RING    3

using f4 = __attribute__((ext_vector_type(4))) float;

#define GLD_LDS16(g, l)                                              \
  __builtin_amdgcn_global_load_lds(                                  \
      (const __attribute__((address_space(1))) void*)(g),            \
      (__attribute__((address_space(3))) void*)(l), 16, 0, 2 /*nt*/)

// ---------------- K1: LDS-ring pool + depthwise 3x3 + GN1 partials ----------
__global__ __launch_bounds__(256) void k1_pool_dw(
    const float* __restrict__ x, const float* __restrict__ wdw,
    float* __restrict__ h1, float* __restrict__ ch_sum,
    float* __restrict__ ch_sumsq) {
  const int bc   = blockIdx.x;          // b*256 + c
  const int c    = bc & (C_ - 1);
  const int tid  = threadIdx.x;
  const int wv   = tid >> 6, lane = tid & 63;
  const float* plane = x + (size_t)bc * (HWIN * HWIN);

  __shared__ __attribute__((aligned(16))) float slots[RING][CHUNK_F]; // 24 KB
  __shared__ float wpart[2][4][32];                                   // 1 KB
  __shared__ float pooled[OHW][OHW + 1];                              // 4.2 KB
  __shared__ float r2[4][2];

  // scalar (uniform) weight loads -> lgkmcnt, keeps vmcnt = staging only
  float w[9];
#pragma unroll
  for (int i = 0; i < 9; ++i) w[i] = wdw[c * 9 + i];

  // wave wv stages floats [wv*512, wv*512+512) of each chunk (rows 2wv,2wv+1)
#define STAGE(t)                                                        \
  do {                                                                  \
    const float* g0 = plane + (size_t)(t) * CHUNK_F + wv * 512 + lane * 4; \
    float* l0 = &slots[(t) % RING][wv * 512];                           \
    GLD_LDS16(g0, l0);                                                  \
    GLD_LDS16(g0 + 256, l0 + 256);                                      \
  } while (0)

  STAGE(0);
  STAGE(1);

#pragma unroll 1
  for (int t = 0; t < NCHUNK; ++t) {
    __builtin_amdgcn_s_barrier();        // separates STAGE(t+2) from compute(t-1)
    if (t + 2 < NCHUNK) {
      STAGE(t + 2);
      asm volatile("s_waitcnt vmcnt(4)" ::: "memory");  // chunk t landed
    } else if (t + 1 < NCHUNK) {
      asm volatile("s_waitcnt vmcnt(2)" ::: "memory");
    } else {
      asm volatile("s_waitcnt vmcnt(0)" ::: "memory");
    }
    __builtin_amdgcn_s_barrier();        // all waves' parts of chunk t landed

    // reduce chunk t: rows wv & wv+4, 4 cols per lane; pair-shfl -> 8-col sum
    {
      const f4* sf = (const f4*)&slots[t % RING][0];
      const f4 v0 = sf[tid];
      const f4 v1 = sf[tid + 256];
      float s = ((v0.x + v0.y) + (v0.z + v0.w)) +
                ((v1.x + v1.y) + (v1.z + v1.w));
      s += __shfl_xor(s, 1);
      if (!(lane & 1)) wpart[t & 1][wv][lane >> 1] = s;
      // combine previous chunk's partials -> pooled row t-1
      if (t > 0 && tid < 32) {
        const int pa = (t - 1) & 1;
        pooled[t - 1][tid] =
            ((wpart[pa][0][tid] + wpart[pa][1][tid]) +
             (wpart[pa][2][tid] + wpart[pa][3][tid])) * (1.f / 64.f);
      }
    }
  }
  __builtin_amdgcn_s_barrier();
  if (tid < 32) {
    pooled[NCHUNK - 1][tid] =
        ((wpart[1][0][tid] + wpart[1][1][tid]) +
         (wpart[1][2][tid] + wpart[1][3][tid])) * (1.f / 64.f);
  }
  __syncthreads();

  // depthwise 3x3 SAME (zero pad) + local stats
  float ls = 0.f, lss = 0.f;
  for (int p = tid; p < NPIX; p += 256) {
    const int oh = p >> 5, ow = p & 31;
    float acc = 0.f;
#pragma unroll
    for (int ky = 0; ky < 3; ++ky) {
      const int y = oh + ky - 1;
      if ((unsigned)y >= OHW) continue;
#pragma unroll
      for (int kx = 0; kx < 3; ++kx) {
        const int xx = ow + kx - 1;
        if ((unsigned)xx >= OHW) continue;
        acc += w[ky * 3 + kx] * pooled[y][xx];
      }
    }
    h1[(size_t)bc * NPIX + p] = acc;
    ls += acc; lss += acc * acc;
  }

  // deterministic block reduce -> per-channel sums
#pragma unroll
  for (int m = 32; m >= 1; m >>= 1) {
    ls  += __shfl_xor(ls, m);
    lss += __shfl_xor(lss, m);
  }
  if (lane == 0) { r2[wv][0] = ls; r2[wv][1] = lss; }
  __syncthreads();
  if (tid == 0) {
    ch_sum[bc]   = (r2[0][0] + r2[1][0]) + (r2[2][0] + r2[3][0]);
    ch_sumsq[bc] = (r2[0][1] + r2[1][1]) + (r2[2][1] + r2[3][1]);
  }
#undef STAGE
}

// -------- K2: GN1 finalize + SiLU + pointwise C->R + GN2 partial stats ------
__global__ __launch_bounds__(256) void k2_pw1(
    const float* __restrict__ h1, const float* __restrict__ ch_sum,
    const float* __restrict__ ch_sumsq, const float* __restrict__ g1,
    const float* __restrict__ b1, const float* __restrict__ w1,
    float* __restrict__ h2, float* __restrict__ st2) {
  const int blk = blockIdx.x;          // b*16 + q
  const int b   = blk >> 4, q = blk & 15;
  const int tid = threadIdx.x;
  const int wv  = tid >> 6, lane = tid & 63;

  __shared__ float musr[8][2];
  __shared__ float sc[C_], sh[C_];
  __shared__ float w1s[R_ * C_];          // 16 KB
  __shared__ float red[4][64][R_ + 1];    // padded: kills bank conflicts

  {
    float cs  = ch_sum[b * C_ + tid];
    float css = ch_sumsq[b * C_ + tid];
#pragma unroll
    for (int m = 16; m >= 1; m >>= 1) {
      cs  += __shfl_xor(cs, m);
      css += __shfl_xor(css, m);
    }
    if ((tid & 31) == 0) {
      const int g = tid >> 5;
      const float mu  = cs * (1.f / 32768.f);
      const float var = css * (1.f / 32768.f) - mu * mu;
      musr[g][0] = mu;
      musr[g][1] = rsqrtf(var + 1e-5f);
    }
  }
  for (int i = tid; i < R_ * C_; i += 256) w1s[i] = w1[i];
  __syncthreads();

  {
    const int g = tid >> 5;
    const float mu = musr[g][0], rs = musr[g][1];
    const float ga = g1[tid];
    sc[tid] = rs * ga;
    sh[tid] = b1[tid] - mu * rs * ga;
  }
  __syncthreads();

  const int hw = q * 64 + lane;
  const float* hp = h1 + (size_t)b * C_ * NPIX + hw;
  const int c0 = wv * 64;
  float acc[R_];
#pragma unroll
  for (int r = 0; r < R_; ++r) acc[r] = 0.f;

#pragma unroll 8
  for (int j = 0; j < 64; ++j) {
    const int cc = c0 + j;
    const float v = hp[(size_t)cc * NPIX];          // coalesced across lanes
    const float u = v * sc[cc] + sh[cc];
    const float t = u / (1.f + __expf(-u));         // SiLU
#pragma unroll
    for (int r = 0; r < R_; ++r) acc[r] += t * w1s[r * C_ + cc];
  }

#pragma unroll
  for (int r = 0; r < R_; ++r) red[wv][lane][r] = acc[r];
  __syncthreads();

  // thread t: pixel p = t>>2, r-group g = t&3 (r = 4g..4g+3)
  const int p = tid >> 2, g = tid & 3;
  float gs = 0.f, gss = 0.f;
  float* h2p = h2 + (size_t)b * R_ * NPIX + q * 64 + p;
#pragma unroll
  for (int j = 0; j < 4; ++j) {
    const int r = g * 4 + j;
    const float v = (red[0][p][r] + red[1][p][r]) + (red[2][p][r] + red[3][p][r]);
    h2p[r * NPIX] = v;
    gs += v; gss += v * v;
  }
#pragma unroll
  for (int m = 4; m <= 32; m <<= 1) {
    gs  += __shfl_xor(gs, m);
    gss += __shfl_xor(gss, m);
  }
  __shared__ float red2[4][4][2];
  if (lane < 4) { red2[wv][lane][0] = gs; red2[wv][lane][1] = gss; }
  __syncthreads();
  if (tid < 8) {
    const int gg = tid >> 1, which = tid & 1;
    st2[blk * 8 + tid] = (red2[0][gg][which] + red2[1][gg][which]) +
                         (red2[2][gg][which] + red2[3][gg][which]);
  }
}

// ---- K3: GN2 finalize + SiLU + pw R->E + softmax + mean + top-2 + renorm ---
__global__ __launch_bounds__(256) void k3_route(
    const float* __restrict__ h2, const float* __restrict__ st2,
    const float* __restrict__ g2, const float* __restrict__ b2,
    const float* __restrict__ w2, const float* __restrict__ bias2,
    float* __restrict__ out) {
  const int b   = blockIdx.x;
  const int tid = threadIdx.x;

  __shared__ float musr[4][2];
  __shared__ float sc2[R_], sh2[R_];
  __shared__ float w2s[E_ * R_ + E_];

  if (tid < 4) {
    float s = 0.f, ss = 0.f;
    for (int qq = 0; qq < 16; ++qq) {
      s  += st2[(b * 16 + qq) * 8 + tid * 2];
      ss += st2[(b * 16 + qq) * 8 + tid * 2 + 1];
    }
    const float mu  = s * (1.f / 4096.f);
    const float var = ss * (1.f / 4096.f) - mu * mu;
    musr[tid][0] = mu;
    musr[tid][1] = rsqrtf(var + 1e-5f);
  }
  if (tid < E_ * R_) w2s[tid] = w2[tid];
  else if (tid < E_ * R_ + E_) w2s[tid] = bias2[tid - E_ * R_];
  __syncthreads();
  if (tid < R_) {
    const int g = tid >> 2;
    const float ga = g2[tid];
    sc2[tid] = musr[g][1] * ga;
    sh2[tid] = b2[tid] - musr[g][0] * musr[g][1] * ga;
  }
  __syncthreads();

  float wa[E_];
#pragma unroll
  for (int e = 0; e < E_; ++e) wa[e] = 0.f;
  const float* hp = h2 + (size_t)b * R_ * NPIX;

  for (int pp = 0; pp < 4; ++pp) {
    const int hw = pp * 256 + tid;
    float t[R_];
#pragma unroll
    for (int r = 0; r < R_; ++r) {
      const float u = hp[r * NPIX + hw] * sc2[r] + sh2[r];
      t[r] = u / (1.f + __expf(-u));
    }
    float lg[E_];
    float mx = -1e30f;
#pragma unroll
    for (int e = 0; e < E_; ++e) {
      float s = w2s[E_ * R_ + e];
#pragma unroll
      for (int r = 0; r < R_; ++r) s += w2s[e * R_ + r] * t[r];
      lg[e] = s;
      mx = fmaxf(mx, s);
    }
    float den = 0.f;
#pragma unroll
    for (int e = 0; e < E_; ++e) { lg[e] = __expf(lg[e] - mx); den += lg[e]; }
    const float inv = 1.f / den;
#pragma unroll
    for (int e = 0; e < E_; ++e) wa[e] += lg[e] * inv;
  }

#pragma unroll
  for (int m = 32; m >= 1; m >>= 1) {
#pragma unroll
    for (int e = 0; e < E_; ++e) wa[e] += __shfl_xor(wa[e], m);
  }
  __shared__ float red[4][E_];
  const int wv = tid >> 6;
  if ((tid & 63) == 0) {
#pragma unroll
    for (int e = 0; e < E_; ++e) red[wv][e] = wa[e];
  }
  __syncthreads();
  __shared__ float pooled[E_];
  if (tid < E_)
    pooled[tid] = ((red[0][tid] + red[1][tid]) + (red[2][tid] + red[3][tid])) * (1.f / 1024.f);
  __syncthreads();

  if (tid == 0) {
    float pv[E_];
#pragma unroll
    for (int e = 0; e < E_; ++e) pv[e] = pooled[e];
    // top-2, strict > keeps lowest index on ties (lax.top_k semantics)
    int i1 = 0; float v1 = pv[0];
    for (int e = 1; e < E_; ++e) if (pv[e] > v1) { v1 = pv[e]; i1 = e; }
    pv[i1] = -1e30f;
    int i2 = 0; float v2 = pv[0];
    for (int e = 1; e < E_; ++e) if (pv[e] > v2) { v2 = pv[e]; i2 = e; }
    const float inv = 1.f / (v1 + v2 + 1e-9f);
    out[b * 2 + 0] = v1 * inv;
    out[b * 2 + 1] = v2 * inv;
    out[32 + b * 2 + 0] = (float)i1;   // indices as fp32 (whole d_out read as f32)
    out[32 + b * 2 + 1] = (float)i2;
  }
}

extern "C" void kernel_launch(void* const* d_in, const int* in_sizes, int n_in,
                              void* d_out, int out_size, void* d_ws, size_t ws_size,
                              hipStream_t stream) {
  const float* x     = (const float*)d_in[0];
  const float* wdw   = (const float*)d_in[1];
  const float* g1    = (const float*)d_in[2];
  const float* b1    = (const float*)d_in[3];
  const float* w1    = (const float*)d_in[4];
  const float* g2    = (const float*)d_in[5];
  const float* b2    = (const float*)d_in[6];
  const float* w2    = (const float*)d_in[7];
  const float* bias2 = (const float*)d_in[8];
  float* out = (float*)d_out;

  char* ws = (char*)d_ws;
  float* h1       = (float*)ws;                              // 16 MiB
  float* h2       = (float*)(ws + (size_t)16 * 1024 * 1024); // 1 MiB
  float* ch_sum   = (float*)(ws + (size_t)17 * 1024 * 1024); // 16 KiB
  float* ch_sumsq = ch_sum + 4096;                           // 16 KiB
  float* st2      = ch_sumsq + 4096;                         // 8 KiB

  hipLaunchKernelGGL(k1_pool_dw, dim3(16 * C_), dim3(256), 0, stream,
                     x, wdw, h1, ch_sum, ch_sumsq);
  hipLaunchKernelGGL(k2_pw1, dim3(256), dim3(256), 0, stream,
                     h1, ch_sum, ch_sumsq, g1, b1, w1, h2, st2);
  hipLaunchKernelGGL(k3_route, dim3(16), dim3(256), 0, stream,
                     h2, st2, g2, b2, w2, bias2, out);
}

// Round 9
// 225.043 us; speedup vs baseline: 1.1339x; 1.0431x over previous
//
#include <hip/hip_runtime.h>
#include <hip/hip_bf16.h>
#include <math.h>

// Pipeline: x[16,256,256,256] --8x8 avgpool--> [16,256,32,32] --dw3x3-->
// GN(8)+SiLU --pw 256->16--> GN(4)+SiLU --pw 16->8 +bias--> softmax(E) -->
// spatial mean --> top-2 + renorm. Memory-bound on the 1.07 GB input read.
//
// FINAL (revert to best-measured R5 config, 225 us):
// K1: fused pool + dw3x3 + GN1 partials. Block sweeps its 256KB plane
//     LINEARLY (one contiguous 8KB front across the 4 waves); NT loads
//     (single-use stream, +30us vs cached, R5<->R7 A/B). Read engine runs at
//     ~5.2 TB/s -- the measured read-path ceiling across 5 structural
//     variants (register/LDS landing, NT/cached, 512..16K streams).
// K2: GN1 finalize + SiLU + pw C->R + GN2 partials
// K3: GN2 finalize + SiLU + pw R->E + softmax + mean + top2

#define C_    256
#define HWIN  256
#define OHW   32
#define NPIX  1024   // 32*32
#define R_    16
#define E_    8

using f4 = __attribute__((ext_vector_type(4))) float;

// ---------------- K1: linear-sweep pool + depthwise 3x3 + GN1 partials ------
__global__ __launch_bounds__(256) void k1_pool_dw(
    const float* __restrict__ x, const float* __restrict__ wdw,
    float* __restrict__ h1, float* __restrict__ ch_sum,
    float* __restrict__ ch_sumsq) {
  const int bc   = blockIdx.x;          // b*256 + c
  const int c    = bc & (C_ - 1);
  const int tid  = threadIdx.x;
  const int wv   = tid >> 6, lane = tid & 63;
  const float* plane = x + (size_t)bc * (HWIN * HWIN);

  // part[pr][w][col]: per-wave 2-row partial sums; pooled combined in place
  __shared__ float part[OHW][4][32];

  // Linear plane sweep: at step pr the block's 4 waves read input rows
  // {8pr+0..3} and {8pr+4..7} -> one contiguous 8KB front.
#pragma unroll 4
  for (int pr = 0; pr < OHW; ++pr) {
    const float* r0 = plane + ((size_t)(8 * pr + wv)) * HWIN + lane * 4;
    const f4 a = __builtin_nontemporal_load(reinterpret_cast<const f4*>(r0));
    const f4 b = __builtin_nontemporal_load(
        reinterpret_cast<const f4*>(r0 + 4 * HWIN));
    const f4 v = a + b;
    float s = (v.x + v.y) + (v.z + v.w);
    s += __shfl_xor(s, 1);                     // 8-col sum for col lane>>1
    if (!(lane & 1)) part[pr][wv][lane >> 1] = s;
  }
  float w[9];
#pragma unroll
  for (int i = 0; i < 9; ++i) w[i] = wdw[c * 9 + i];
  __syncthreads();

  // combine 4 wave-partials -> pooled value, in place over part[pr][0][col]
  for (int p = tid; p < NPIX; p += 256) {
    const int oh = p >> 5, ow = p & 31;
    const float v = ((part[oh][0][ow] + part[oh][1][ow]) +
                     (part[oh][2][ow] + part[oh][3][ow])) * (1.f / 64.f);
    part[oh][0][ow] = v;                       // each (oh,ow) owned by 1 thread
  }
  __syncthreads();

#define SM(y, xx) part[y][0][xx]
  // depthwise 3x3 SAME (zero pad) + local stats
  float ls = 0.f, lss = 0.f;
  for (int p = tid; p < NPIX; p += 256) {
    const int oh = p >> 5, ow = p & 31;
    float acc = 0.f;
#pragma unroll
    for (int ky = 0; ky < 3; ++ky) {
      const int y = oh + ky - 1;
      if ((unsigned)y >= OHW) continue;
#pragma unroll
      for (int kx = 0; kx < 3; ++kx) {
        const int xx = ow + kx - 1;
        if ((unsigned)xx >= OHW) continue;
        acc += w[ky * 3 + kx] * SM(y, xx);
      }
    }
    h1[(size_t)bc * NPIX + p] = acc;
    ls += acc; lss += acc * acc;
  }
#undef SM

  // deterministic block reduce -> per-channel sums
#pragma unroll
  for (int m = 32; m >= 1; m >>= 1) {
    ls  += __shfl_xor(ls, m);
    lss += __shfl_xor(lss, m);
  }
  __shared__ float r2[4][2];
  if (lane == 0) { r2[wv][0] = ls; r2[wv][1] = lss; }
  __syncthreads();
  if (tid == 0) {
    ch_sum[bc]   = (r2[0][0] + r2[1][0]) + (r2[2][0] + r2[3][0]);
    ch_sumsq[bc] = (r2[0][1] + r2[1][1]) + (r2[2][1] + r2[3][1]);
  }
}

// -------- K2: GN1 finalize + SiLU + pointwise C->R + GN2 partial stats ------
__global__ __launch_bounds__(256) void k2_pw1(
    const float* __restrict__ h1, const float* __restrict__ ch_sum,
    const float* __restrict__ ch_sumsq, const float* __restrict__ g1,
    const float* __restrict__ b1, const float* __restrict__ w1,
    float* __restrict__ h2, float* __restrict__ st2) {
  const int blk = blockIdx.x;          // b*16 + q
  const int b   = blk >> 4, q = blk & 15;
  const int tid = threadIdx.x;
  const int wv  = tid >> 6, lane = tid & 63;

  __shared__ float musr[8][2];
  __shared__ float sc[C_], sh[C_];
  __shared__ float w1s[R_ * C_];          // 16 KB
  __shared__ float red[4][64][R_ + 1];    // padded: kills bank conflicts

  {
    float cs  = ch_sum[b * C_ + tid];
    float css = ch_sumsq[b * C_ + tid];
#pragma unroll
    for (int m = 16; m >= 1; m >>= 1) {
      cs  += __shfl_xor(cs, m);
      css += __shfl_xor(css, m);
    }
    if ((tid & 31) == 0) {
      const int g = tid >> 5;
      const float mu  = cs * (1.f / 32768.f);
      const float var = css * (1.f / 32768.f) - mu * mu;
      musr[g][0] = mu;
      musr[g][1] = rsqrtf(var + 1e-5f);
    }
  }
  for (int i = tid; i < R_ * C_; i += 256) w1s[i] = w1[i];
  __syncthreads();

  {
    const int g = tid >> 5;
    const float mu = musr[g][0], rs = musr[g][1];
    const float ga = g1[tid];
    sc[tid] = rs * ga;
    sh[tid] = b1[tid] - mu * rs * ga;
  }
  __syncthreads();

  const int hw = q * 64 + lane;
  const float* hp = h1 + (size_t)b * C_ * NPIX + hw;
  const int c0 = wv * 64;
  float acc[R_];
#pragma unroll
  for (int r = 0; r < R_; ++r) acc[r] = 0.f;

#pragma unroll 8
  for (int j = 0; j < 64; ++j) {
    const int cc = c0 + j;
    const float v = hp[(size_t)cc * NPIX];          // coalesced across lanes
    const float u = v * sc[cc] + sh[cc];
    const float t = u / (1.f + __expf(-u));         // SiLU
#pragma unroll
    for (int r = 0; r < R_; ++r) acc[r] += t * w1s[r * C_ + cc];
  }

#pragma unroll
  for (int r = 0; r < R_; ++r) red[wv][lane][r] = acc[r];
  __syncthreads();

  // thread t: pixel p = t>>2, r-group g = t&3 (r = 4g..4g+3)
  const int p = tid >> 2, g = tid & 3;
  float gs = 0.f, gss = 0.f;
  float* h2p = h2 + (size_t)b * R_ * NPIX + q * 64 + p;
#pragma unroll
  for (int j = 0; j < 4; ++j) {
    const int r = g * 4 + j;
    const float v = (red[0][p][r] + red[1][p][r]) + (red[2][p][r] + red[3][p][r]);
    h2p[r * NPIX] = v;
    gs += v; gss += v * v;
  }
#pragma unroll
  for (int m = 4; m <= 32; m <<= 1) {
    gs  += __shfl_xor(gs, m);
    gss += __shfl_xor(gss, m);
  }
  __shared__ float red2[4][4][2];
  if (lane < 4) { red2[wv][lane][0] = gs; red2[wv][lane][1] = gss; }
  __syncthreads();
  if (tid < 8) {
    const int gg = tid >> 1, which = tid & 1;
    st2[blk * 8 + tid] = (red2[0][gg][which] + red2[1][gg][which]) +
                         (red2[2][gg][which] + red2[3][gg][which]);
  }
}

// ---- K3: GN2 finalize + SiLU + pw R->E + softmax + mean + top-2 + renorm ---
__global__ __launch_bounds__(256) void k3_route(
    const float* __restrict__ h2, const float* __restrict__ st2,
    const float* __restrict__ g2, const float* __restrict__ b2,
    const float* __restrict__ w2, const float* __restrict__ bias2,
    float* __restrict__ out) {
  const int b   = blockIdx.x;
  const int tid = threadIdx.x;

  __shared__ float musr[4][2];
  __shared__ float sc2[R_], sh2[R_];
  __shared__ float w2s[E_ * R_ + E_];

  if (tid < 4) {
    float s = 0.f, ss = 0.f;
    for (int qq = 0; qq < 16; ++qq) {
      s  += st2[(b * 16 + qq) * 8 + tid * 2];
      ss += st2[(b * 16 + qq) * 8 + tid * 2 + 1];
    }
    const float mu  = s * (1.f / 4096.f);
    const float var = ss * (1.f / 4096.f) - mu * mu;
    musr[tid][0] = mu;
    musr[tid][1] = rsqrtf(var + 1e-5f);
  }
  if (tid < E_ * R_) w2s[tid] = w2[tid];
  else if (tid < E_ * R_ + E_) w2s[tid] = bias2[tid - E_ * R_];
  __syncthreads();
  if (tid < R_) {
    const int g = tid >> 2;
    const float ga = g2[tid];
    sc2[tid] = musr[g][1] * ga;
    sh2[tid] = b2[tid] - musr[g][0] * musr[g][1] * ga;
  }
  __syncthreads();

  float wa[E_];
#pragma unroll
  for (int e = 0; e < E_; ++e) wa[e] = 0.f;
  const float* hp = h2 + (size_t)b * R_ * NPIX;

  for (int pp = 0; pp < 4; ++pp) {
    const int hw = pp * 256 + tid;
    float t[R_];
#pragma unroll
    for (int r = 0; r < R_; ++r) {
      const float u = hp[r * NPIX + hw] * sc2[r] + sh2[r];
      t[r] = u / (1.f + __expf(-u));
    }
    float lg[E_];
    float mx = -1e30f;
#pragma unroll
    for (int e = 0; e < E_; ++e) {
      float s = w2s[E_ * R_ + e];
#pragma unroll
      for (int r = 0; r < R_; ++r) s += w2s[e * R_ + r] * t[r];
      lg[e] = s;
      mx = fmaxf(mx, s);
    }
    float den = 0.f;
#pragma unroll
    for (int e = 0; e < E_; ++e) { lg[e] = __expf(lg[e] - mx); den += lg[e]; }
    const float inv = 1.f / den;
#pragma unroll
    for (int e = 0; e < E_; ++e) wa[e] += lg[e] * inv;
  }

#pragma unroll
  for (int m = 32; m >= 1; m >>= 1) {
#pragma unroll
    for (int e = 0; e < E_; ++e) wa[e] += __shfl_xor(wa[e], m);
  }
  __shared__ float red[4][E_];
  const int wv = tid >> 6;
  if ((tid & 63) == 0) {
#pragma unroll
    for (int e = 0; e < E_; ++e) red[wv][e] = wa[e];
  }
  __syncthreads();
  __shared__ float pooled[E_];
  if (tid < E_)
    pooled[tid] = ((red[0][tid] + red[1][tid]) + (red[2][tid] + red[3][tid])) * (1.f / 1024.f);
  __syncthreads();

  if (tid == 0) {
    float pv[E_];
#pragma unroll
    for (int e = 0; e < E_; ++e) pv[e] = pooled[e];
    // top-2, strict > keeps lowest index on ties (lax.top_k semantics)
    int i1 = 0; float v1 = pv[0];
    for (int e = 1; e < E_; ++e) if (pv[e] > v1) { v1 = pv[e]; i1 = e; }
    pv[i1] = -1e30f;
    int i2 = 0; float v2 = pv[0];
    for (int e = 1; e < E_; ++e) if (pv[e] > v2) { v2 = pv[e]; i2 = e; }
    const float inv = 1.f / (v1 + v2 + 1e-9f);
    out[b * 2 + 0] = v1 * inv;
    out[b * 2 + 1] = v2 * inv;
    out[32 + b * 2 + 0] = (float)i1;   // indices as fp32 (whole d_out read as f32)
    out[32 + b * 2 + 1] = (float)i2;
  }
}

extern "C" void kernel_launch(void* const* d_in, const int* in_sizes, int n_in,
                              void* d_out, int out_size, void* d_ws, size_t ws_size,
                              hipStream_t stream) {
  const float* x     = (const float*)d_in[0];
  const float* wdw   = (const float*)d_in[1];
  const float* g1    = (const float*)d_in[2];
  const float* b1    = (const float*)d_in[3];
  const float* w1    = (const float*)d_in[4];
  const float* g2    = (const float*)d_in[5];
  const float* b2    = (const float*)d_in[6];
  const float* w2    = (const float*)d_in[7];
  const float* bias2 = (const float*)d_in[8];
  float* out = (float*)d_out;

  char* ws = (char*)d_ws;
  float* h1       = (float*)ws;                              // 16 MiB
  float* h2       = (float*)(ws + (size_t)16 * 1024 * 1024); // 1 MiB
  float* ch_sum   = (float*)(ws + (size_t)17 * 1024 * 1024); // 16 KiB
  float* ch_sumsq = ch_sum + 4096;                           // 16 KiB
  float* st2      = ch_sumsq + 4096;                         // 8 KiB

  hipLaunchKernelGGL(k1_pool_dw, dim3(16 * C_), dim3(256), 0, stream,
                     x, wdw, h1, ch_sum, ch_sumsq);
  hipLaunchKernelGGL(k2_pw1, dim3(256), dim3(256), 0, stream,
                     h1, ch_sum, ch_sumsq, g1, b1, w1, h2, st2);
  hipLaunchKernelGGL(k3_route, dim3(16), dim3(256), 0, stream,
                     h2, st2, g2, b2, w2, bias2, out);
}